// Round 4
// baseline (799.473 us; speedup 1.0000x reference)
//
#include <hip/hip_runtime.h>
#include <cstdint>
#include <cstddef>

#define Nn 50000
#define Ne 800000
#define Ng 1024
#define NFd 32
#define Rr 4
#define Hd 64
#define Od 16
#define MAXD 10
#define NPAD16 (Nn + 16 * (MAXD + 1))
#define NSEG (Nn * Rr)
#define SCAN_BLK ((NSEG + 255) / 256)

__device__ __forceinline__ float reluf(float v) { return v > 0.f ? v : 0.f; }

// ---- per-edge relation argmax -> segment id (tgt*R+rel) + segment histogram ----
__global__ void k_rel_seg(const float4* __restrict__ ea, const int* __restrict__ eidx,
                          int* __restrict__ seg, int* __restrict__ cnt) {
    int e = blockIdx.x * 256 + threadIdx.x;
    if (e >= Ne) return;
    float4 a = ea[e];
    int bi = 0; float bv = a.x;
    if (a.y > bv) { bv = a.y; bi = 1; }
    if (a.z > bv) { bv = a.z; bi = 2; }
    if (a.w > bv) { bv = a.w; bi = 3; }
    int s = eidx[Ne + e] * Rr + bi;
    seg[e] = s;
    atomicAdd(&cnt[s], 1);
}

// ---- 3-kernel exclusive scan over cnt[NSEG] -> off[NSEG+1] ----
__global__ void k_scan1(const int* __restrict__ cnt, int* __restrict__ off,
                        int* __restrict__ bsum) {
    __shared__ int s[256];
    int t = threadIdx.x;
    int idx = blockIdx.x * 256 + t;
    int v = (idx < NSEG) ? cnt[idx] : 0;
    s[t] = v;
    __syncthreads();
    #pragma unroll
    for (int o = 1; o < 256; o <<= 1) {
        int x = (t >= o) ? s[t - o] : 0;
        __syncthreads();
        s[t] += x;
        __syncthreads();
    }
    if (idx < NSEG) off[idx] = s[t] - v;            // exclusive
    if (t == 255) bsum[blockIdx.x] = s[255];
}

__global__ void k_scan2(int* __restrict__ bsum) {
    __shared__ int s[1024];
    int t = threadIdx.x;
    int v = (t < SCAN_BLK) ? bsum[t] : 0;
    s[t] = v;
    __syncthreads();
    #pragma unroll
    for (int o = 1; o < 1024; o <<= 1) {
        int x = (t >= o) ? s[t - o] : 0;
        __syncthreads();
        s[t] += x;
        __syncthreads();
    }
    if (t < SCAN_BLK) bsum[t] = s[t] - v;           // exclusive block bases
}

__global__ void k_scan3(int* __restrict__ off, const int* __restrict__ bsum,
                        int* __restrict__ fill) {
    int idx = blockIdx.x * 256 + threadIdx.x;
    if (idx == 0) off[NSEG] = Ne;
    if (idx >= NSEG) return;
    int v = off[idx] + bsum[blockIdx.x];
    off[idx] = v;
    fill[idx] = v;
}

// ---- scatter edges into segment-sorted order (store src only) ----
__global__ void k_scatter(const int* __restrict__ eidx, const int* __restrict__ seg,
                          int* __restrict__ fill, int* __restrict__ sorted_src) {
    int e = blockIdx.x * 256 + threadIdx.x;
    if (e >= Ne) return;
    int pos = atomicAdd(&fill[seg[e]], 1);
    sorted_src[pos] = eidx[e];
}

// ---- embedding lookup: wave per node; writes relu'd row (raw h0 never consumed) ----
__global__ void k_embed(const float* __restrict__ x, const float* __restrict__ emb,
                        float* __restrict__ h) {
    int wave = (blockIdx.x * 256 + threadIdx.x) >> 6;
    int lane = threadIdx.x & 63;
    if (wave >= Nn) return;
    float v = (lane < NFd) ? x[(size_t)wave * NFd + lane] : -1e30f;
    int idx = lane;
    #pragma unroll
    for (int off = 16; off >= 1; off >>= 1) {
        float ov = __shfl_down(v, off);
        int oi = __shfl_down(idx, off);
        if (ov > v || (ov == v && oi < idx)) { v = ov; idx = oi; }
    }
    idx = __shfl(idx, 0);
    h[(size_t)wave * Hd + lane] = reluf(emb[(size_t)idx * Hd + lane]);
}

// ---- degree bucketing from CSR offsets (LDS hist, 11 global atomics/block) ----
__global__ void k_bucket_count(const int* __restrict__ off, int* __restrict__ bcnt) {
    __shared__ int hist[16];
    if (threadIdx.x < 16) hist[threadIdx.x] = 0;
    __syncthreads();
    int n = blockIdx.x * 256 + threadIdx.x;
    if (n < Nn) {
        int d = min(off[n * Rr + Rr] - off[n * Rr], MAXD);
        atomicAdd(&hist[d], 1);
    }
    __syncthreads();
    if (threadIdx.x < 16) {
        int h = hist[threadIdx.x];
        if (h > 0) atomicAdd(&bcnt[threadIdx.x], h);
    }
}

__global__ void k_bucket_prefix(const int* __restrict__ bcnt, int* __restrict__ bbase) {
    if (threadIdx.x == 0 && blockIdx.x == 0) {
        int run = 0;
        for (int d = 0; d <= MAXD; d++) { bbase[d] = run; run += (bcnt[d] + 15) & ~15; }
    }
}

__global__ void k_bucket_scatter(const int* __restrict__ off, const int* __restrict__ bbase,
                                 int* __restrict__ bfill, int* __restrict__ order) {
    __shared__ int hist[16];
    __shared__ int base[16];
    if (threadIdx.x < 16) hist[threadIdx.x] = 0;
    __syncthreads();
    int n = blockIdx.x * 256 + threadIdx.x;
    int d = 0, rank = 0;
    bool valid = (n < Nn);
    if (valid) {
        d = min(off[n * Rr + Rr] - off[n * Rr], MAXD);
        rank = atomicAdd(&hist[d], 1);
    }
    __syncthreads();
    if (threadIdx.x < 16) {
        int h = hist[threadIdx.x];
        base[threadIdx.x] = (h > 0) ? atomicAdd(&bfill[threadIdx.x], h) : 0;
    }
    __syncthreads();
    if (valid) order[bbase[d] + base[d] + rank] = n | (d << 20);
}

// ---- RGCN: segmented MEAN of h[src] per (tgt,rel); wave per segment (h pre-relu'd) ----
__global__ void k_rgcn_agg(const float* __restrict__ hin, const int* __restrict__ off,
                           const int* __restrict__ sorted_src, float* __restrict__ agg) {
    int s = __builtin_amdgcn_readfirstlane((blockIdx.x * 256 + threadIdx.x) >> 6);
    int lane = threadIdx.x & 63;
    if (s >= NSEG) return;
    int s0 = __builtin_amdgcn_readfirstlane(off[s]);
    int s1 = __builtin_amdgcn_readfirstlane(off[s + 1]);
    float sum = 0.f;
    for (int e = s0; e < s1; e++) {
        int src = __builtin_amdgcn_readfirstlane(sorted_src[e]);
        sum += hin[(size_t)src * Hd + lane];
    }
    float inv = (s1 > s0) ? 1.f / (float)(s1 - s0) : 0.f;
    agg[(size_t)s * Hd + lane] = sum * inv;
}

// ---- RGCN transform: out = relu(sum_r mean_r @ W[r] + h @ Wroot + b) ----
// 16 nodes/wave: weights from L2 amortized x16, inputs via scalar (uniform) loads.
__global__ void k_rgcn_xform(const float* __restrict__ hin, const float* __restrict__ agg,
                             const float* __restrict__ W, const float* __restrict__ Wroot,
                             const float* __restrict__ bias, float* __restrict__ hout) {
    int wave = __builtin_amdgcn_readfirstlane((blockIdx.x * 256 + threadIdx.x) >> 6);
    int lane = threadIdx.x & 63;
    int n0 = wave * 16;
    if (n0 >= Nn) return;
    float bj = bias[lane];
    float acc[16];
    #pragma unroll
    for (int i = 0; i < 16; i++) acc[i] = bj;
    // root term (hin pre-relu'd)
    const float* hb = hin + (size_t)n0 * Hd;
    for (int kc = 0; kc < Hd; kc += 4) {
        float w0 = Wroot[(kc + 0) * Hd + lane];
        float w1 = Wroot[(kc + 1) * Hd + lane];
        float w2 = Wroot[(kc + 2) * Hd + lane];
        float w3 = Wroot[(kc + 3) * Hd + lane];
        #pragma unroll
        for (int i = 0; i < 16; i++) {
            const float4 iv = *(const float4*)(hb + i * Hd + kc);
            acc[i] += iv.x * w0 + iv.y * w1 + iv.z * w2 + iv.w * w3;
        }
    }
    // relation terms (agg already holds the mean)
    const float* ab = agg + (size_t)n0 * Rr * Hd;
    for (int r = 0; r < Rr; r++) {
        const float* Wp = W + (size_t)r * Hd * Hd;
        for (int kc = 0; kc < Hd; kc += 4) {
            float w0 = Wp[(kc + 0) * Hd + lane];
            float w1 = Wp[(kc + 1) * Hd + lane];
            float w2 = Wp[(kc + 2) * Hd + lane];
            float w3 = Wp[(kc + 3) * Hd + lane];
            #pragma unroll
            for (int i = 0; i < 16; i++) {
                const float4 iv = *(const float4*)(ab + ((size_t)i * Rr + r) * Hd + kc);
                acc[i] += iv.x * w0 + iv.y * w1 + iv.z * w2 + iv.w * w3;
            }
        }
    }
    #pragma unroll
    for (int i = 0; i < 16; i++) hout[(size_t)(n0 + i) * Hd + lane] = reluf(acc[i]);
}

// ---- MFConv: segmented SUM of h[src] per tgt (h already relu'd); wave per node ----
__global__ void k_mf_agg(const float* __restrict__ hin, const int* __restrict__ off,
                         const int* __restrict__ sorted_src, float* __restrict__ agg2) {
    int n = __builtin_amdgcn_readfirstlane((blockIdx.x * 256 + threadIdx.x) >> 6);
    int lane = threadIdx.x & 63;
    if (n >= Nn) return;
    int s0 = __builtin_amdgcn_readfirstlane(off[n * Rr]);
    int s1 = __builtin_amdgcn_readfirstlane(off[n * Rr + Rr]);
    float sum = 0.f;
    for (int e = s0; e < s1; e++) {
        int src = __builtin_amdgcn_readfirstlane(sorted_src[e]);
        sum += hin[(size_t)src * Hd + lane];
    }
    agg2[(size_t)n * Hd + lane] = sum;
}

// ---- MFConv transform: degree-bucketed, 16 nodes/wave share Wl[d]/Wr[d] ----
__global__ void k_mf_xform(const float* __restrict__ hin, const float* __restrict__ agg2,
                           const int* __restrict__ order, const float* __restrict__ Wl,
                           const float* __restrict__ bl, const float* __restrict__ Wr,
                           float* __restrict__ hout, int relu_out) {
    int wave = __builtin_amdgcn_readfirstlane((blockIdx.x * 256 + threadIdx.x) >> 6);
    int lane = threadIdx.x & 63;
    int g0 = wave * 16;
    if (g0 >= NPAD16) return;
    int ent[16];
    #pragma unroll
    for (int i = 0; i < 16; i++) ent[i] = order[g0 + i];
    int d = -1;
    #pragma unroll
    for (int i = 15; i >= 0; i--) if (ent[i] >= 0) d = ent[i] >> 20;
    if (d < 0) return;
    int n[16];
    #pragma unroll
    for (int i = 0; i < 16; i++) n[i] = (ent[i] >= 0) ? (ent[i] & 0xFFFFF) : 0;
    const float* wl = Wl + (size_t)d * Hd * Hd;
    const float* wr = Wr + (size_t)d * Hd * Hd;
    float acc[16];
    #pragma unroll
    for (int i = 0; i < 16; i++) acc[i] = 0.f;
    for (int kc = 0; kc < Hd; kc += 4) {
        float a0 = wl[(kc + 0) * Hd + lane];
        float a1 = wl[(kc + 1) * Hd + lane];
        float a2 = wl[(kc + 2) * Hd + lane];
        float a3 = wl[(kc + 3) * Hd + lane];
        float b0 = wr[(kc + 0) * Hd + lane];
        float b1 = wr[(kc + 1) * Hd + lane];
        float b2 = wr[(kc + 2) * Hd + lane];
        float b3 = wr[(kc + 3) * Hd + lane];
        #pragma unroll
        for (int i = 0; i < 16; i++) {
            const float4 av = *(const float4*)(agg2 + (size_t)n[i] * Hd + kc);
            const float4 hv = *(const float4*)(hin + (size_t)n[i] * Hd + kc);
            acc[i] += av.x * a0 + av.y * a1 + av.z * a2 + av.w * a3
                    + hv.x * b0 + hv.y * b1 + hv.z * b2 + hv.w * b3;
        }
    }
    float bb = bl[d * Hd + lane];
    #pragma unroll
    for (int i = 0; i < 16; i++)
        if (ent[i] >= 0) {
            float v = acc[i] + bb;
            hout[(size_t)n[i] * Hd + lane] = relu_out ? reluf(v) : v;
        }
}

// ---- global add pool (batch_idx is sorted -> mostly single fused atomic) ----
__global__ void k_pool(const float* __restrict__ h, const int* __restrict__ batch,
                       float* __restrict__ g) {
    int wave = __builtin_amdgcn_readfirstlane((blockIdx.x * 256 + threadIdx.x) >> 6);
    int lane = threadIdx.x & 63;
    int n0 = wave * 4;
    if (n0 >= Nn) return;
    int b0 = batch[n0], b1 = batch[n0 + 1], b2 = batch[n0 + 2], b3 = batch[n0 + 3];
    float v0 = h[(size_t)n0 * Hd + lane];
    float v1 = h[(size_t)(n0 + 1) * Hd + lane];
    float v2 = h[(size_t)(n0 + 2) * Hd + lane];
    float v3 = h[(size_t)(n0 + 3) * Hd + lane];
    if (b0 == b1 && b0 == b2 && b0 == b3) {
        unsafeAtomicAdd(&g[(size_t)b0 * Hd + lane], v0 + v1 + v2 + v3);
    } else {
        unsafeAtomicAdd(&g[(size_t)b0 * Hd + lane], v0);
        unsafeAtomicAdd(&g[(size_t)b1 * Hd + lane], v1);
        unsafeAtomicAdd(&g[(size_t)b2 * Hd + lane], v2);
        unsafeAtomicAdd(&g[(size_t)b3 * Hd + lane], v3);
    }
}

// ---- head: relu(g@lin1+b1)@lin2+b2, one wave per graph ----
__global__ void k_head(const float* __restrict__ g, const float* __restrict__ w1,
                       const float* __restrict__ b1, const float* __restrict__ w2,
                       const float* __restrict__ b2, float* __restrict__ out) {
    __shared__ float t[4][Hd];
    int wv = threadIdx.x >> 6;
    int lane = threadIdx.x & 63;
    int gi = blockIdx.x * 4 + wv;
    float acc = b1[lane];
    for (int k = 0; k < Hd; k++) acc += g[(size_t)gi * Hd + k] * w1[k * Hd + lane];
    t[wv][lane] = reluf(acc);
    __syncthreads();
    if (lane < Od) {
        float o = b2[lane];
        for (int k = 0; k < Hd; k++) o += t[wv][k] * w2[k * Od + lane];
        out[(size_t)gi * Od + lane] = o;
    }
}

extern "C" void kernel_launch(void* const* d_in, const int* in_sizes, int n_in,
                              void* d_out, int out_size, void* d_ws, size_t ws_size,
                              hipStream_t stream) {
    const float* x      = (const float*)d_in[0];
    const float* ea     = (const float*)d_in[1];
    const int*   eidx   = (const int*)d_in[2];
    const int*   batch  = (const int*)d_in[3];
    const float* emb    = (const float*)d_in[4];
    const float* lin1_w = (const float*)d_in[5];
    const float* lin1_b = (const float*)d_in[6];
    const float* lin2_w = (const float*)d_in[7];
    const float* lin2_b = (const float*)d_in[8];
    const float* rgcn_w[2]    = {(const float*)d_in[9],  (const float*)d_in[15]};
    const float* rgcn_root[2] = {(const float*)d_in[10], (const float*)d_in[16]};
    const float* rgcn_b[2]    = {(const float*)d_in[11], (const float*)d_in[17]};
    const float* mf_wl[2]     = {(const float*)d_in[12], (const float*)d_in[18]};
    const float* mf_bl[2]     = {(const float*)d_in[13], (const float*)d_in[19]};
    const float* mf_wr[2]     = {(const float*)d_in[14], (const float*)d_in[20]};

    char* p = (char*)d_ws;
    float* h0   = (float*)p; p += sizeof(float) * (size_t)Nn * Hd;
    float* h1   = (float*)p; p += sizeof(float) * (size_t)Nn * Hd;
    float* agg  = (float*)p; p += sizeof(float) * (size_t)NSEG * Hd;
    float* gbuf = (float*)p; p += sizeof(float) * (size_t)Ng * Hd;
    int* seg    = (int*)p;   p += sizeof(int) * (size_t)Ne;
    int* ssrc   = (int*)p;   p += sizeof(int) * (size_t)Ne;
    int* cnt    = (int*)p;   p += sizeof(int) * (size_t)NSEG;   // contiguous with bcnt/bfill
    int* bcnt   = (int*)p;   p += sizeof(int) * 16;
    int* bfill  = (int*)p;   p += sizeof(int) * 16;
    int* off    = (int*)p;   p += sizeof(int) * (size_t)(NSEG + 1);
    int* fill   = (int*)p;   p += sizeof(int) * (size_t)NSEG;
    int* bsum   = (int*)p;   p += sizeof(int) * 1024;
    int* bbase  = (int*)p;   p += sizeof(int) * 16;
    int* order  = (int*)p;   p += sizeof(int) * (size_t)NPAD16;

    hipMemsetAsync(cnt, 0, sizeof(int) * ((size_t)NSEG + 32), stream);
    hipMemsetAsync(order, 0xFF, sizeof(int) * (size_t)NPAD16, stream);
    hipMemsetAsync(gbuf, 0, sizeof(float) * (size_t)Ng * Hd, stream);

    k_rel_seg<<<Ne / 256, 256, 0, stream>>>((const float4*)ea, eidx, seg, cnt);
    k_scan1<<<SCAN_BLK, 256, 0, stream>>>(cnt, off, bsum);
    k_scan2<<<1, 1024, 0, stream>>>(bsum);
    k_scan3<<<SCAN_BLK, 256, 0, stream>>>(off, bsum, fill);
    k_scatter<<<Ne / 256, 256, 0, stream>>>(eidx, seg, fill, ssrc);
    k_embed<<<Nn / 4, 256, 0, stream>>>(x, emb, h0);
    k_bucket_count<<<(Nn + 255) / 256, 256, 0, stream>>>(off, bcnt);
    k_bucket_prefix<<<1, 64, 0, stream>>>(bcnt, bbase);
    k_bucket_scatter<<<(Nn + 255) / 256, 256, 0, stream>>>(off, bbase, bfill, order);

    float* hin = h0;
    float* hout = h1;
    for (int b = 0; b < 2; b++) {
        k_rgcn_agg<<<NSEG / 4, 256, 0, stream>>>(hin, off, ssrc, agg);
        k_rgcn_xform<<<(Nn / 16 + 3) / 4, 256, 0, stream>>>(hin, agg, rgcn_w[b], rgcn_root[b],
                                                            rgcn_b[b], hout);
        k_mf_agg<<<Nn / 4, 256, 0, stream>>>(hout, off, ssrc, agg);
        k_mf_xform<<<(NPAD16 / 16 + 3) / 4, 256, 0, stream>>>(hout, agg, order, mf_wl[b],
                                                              mf_bl[b], mf_wr[b], hin,
                                                              b == 0 ? 1 : 0);
        // block output is back in hin for the next block (relu'd for b=0, raw for b=1)
    }
    k_pool<<<Nn / 16, 256, 0, stream>>>(hin, batch, gbuf);
    k_head<<<Ng / 4, 256, 0, stream>>>(gbuf, lin1_w, lin1_b, lin2_w, lin2_b, (float*)d_out);
}